// Round 1
// baseline (151.614 us; speedup 1.0000x reference)
//
#include <hip/hip_runtime.h>
#include <math.h>

// Problem constants (B=8, T=4096, D=256, K=1024)
#define NTOK   32768
#define NDIM   256
#define NCODE  1024
#define CHUNK  4096           // f16 per (strip,kc8) chunk: 128 codes x 32 dims = 8 KB

typedef _Float16 f16x8 __attribute__((ext_vector_type(8)));
typedef float    f32x4 __attribute__((ext_vector_type(4)));

// async global->LDS DMA, 16 B per lane; LDS dst is wave-uniform base + lane*16
__device__ __forceinline__ void gld_lds16(const void* g, void* l) {
    __builtin_amdgcn_global_load_lds(
        (const __attribute__((address_space(1))) void*)g,
        (__attribute__((address_space(3))) void*)l, 16, 0, 0);
}

// ---------------------------------------------------------------------------
// Prep: split codebook (fp32) into f16 hi/lo planes, blocked k-major layout.
// NEW within-chunk layout (bank-conflict-free for the main kernel's reads):
//   chunk = (strip = row/128, kc8 = dim/32); within chunk:
//   off_f16 = (r>>4)*512 + (g&3)*128 + (r&15)*8     (r = row%128, g&3 = k-quad)
// A wave's ds_read_b128 of one 16-row tile is then a sequential 1 KB region.
// Plus exact fp32 row norms. ~1 MB total.
// ---------------------------------------------------------------------------
__global__ __launch_bounds__(256) void prep_cb(
        const float* __restrict__ cb,
        _Float16* __restrict__ ch, _Float16* __restrict__ cl,
        float* __restrict__ csq) {
    const int L   = blockIdx.x * 256 + threadIdx.x;   // 0..32767
    const int row = L >> 5;                           // code 0..1023
    const int g   = L & 31;                           // 8-elem group in 256 dims

    const float* src = cb + (size_t)row * NDIM + g * 8;
    float4 a0 = *(const float4*)src;
    float4 a1 = *(const float4*)(src + 4);
    float v[8] = {a0.x, a0.y, a0.z, a0.w, a1.x, a1.y, a1.z, a1.w};
    f16x8 hi, lo;
    float s = 0.f;
    #pragma unroll
    for (int e = 0; e < 8; ++e) {
        _Float16 h = (_Float16)v[e];
        hi[e] = h;
        lo[e] = (_Float16)(v[e] - (float)h);
        s += v[e] * v[e];
    }
    const int r = row & 127;
    const size_t dst = (size_t)((row >> 7) * 8 + (g >> 2)) * CHUNK
                     + (r >> 4) * 512 + (g & 3) * 128 + (r & 15) * 8;
    *(f16x8*)&ch[dst] = hi;
    *(f16x8*)&cl[dst] = lo;
    #pragma unroll
    for (int off = 16; off > 0; off >>= 1) s += __shfl_down(s, off, 32);
    if ((threadIdx.x & 31) == 0) csq[row] = s;
}

// ---------------------------------------------------------------------------
// Main: A-stationary fused VQ, 128 tokens/block, 512 threads = 8 waves in a
// 4x2 (my,nx) grid. Wave (my,nx): token rows [my*32, my*32+32) register-
// resident for full K=256; code-column half nx of every strip.
// Double-buffered LDS halves (2 x 64 KB = 128 KB) with counted-vmcnt
// prefetch: stage half h+1 while computing half h; vmcnt never drains to 0
// in the main loop. B-frag ds_read_b128 is conflict-free via the tile-major
// chunk layout produced by prep_cb.
// 3-pass f16 MFMA (ah.bh + al.bh + ah.bl); per-lane running argmin/strip.
// Layouts (verified prior session): A/B frag [row=lane&15][k=(lane>>4)*8+j];
// D col=lane&15, row=(lane>>4)*4+reg.
// ---------------------------------------------------------------------------

#define STAGE(h, buf)                                                          \
    do {                                                                       \
        const size_t _sb = (size_t)(h) * 16384 + (size_t)tid * 8;              \
        _Pragma("unroll")                                                      \
        for (int _i = 0; _i < 4; ++_i) {                                       \
            gld_lds16(ch + _sb + _i * 4096, &Bs[buf][0][w * 512 + _i * 4096]); \
            gld_lds16(cl + _sb + _i * 4096, &Bs[buf][1][w * 512 + _i * 4096]); \
        }                                                                      \
    } while (0)

#define COMPUTE(kh, buf)                                                       \
    do {                                                                       \
        _Pragma("unroll")                                                      \
        for (int _k4 = 0; _k4 < 4; ++_k4) {                                    \
            f16x8 fbh[4], fbl[4];                                              \
            _Pragma("unroll")                                                  \
            for (int _t = 0; _t < 4; ++_t) {                                   \
                const int _off = _k4 * 4096 + (nx * 4 + _t) * 512              \
                               + quad * 128 + lr * 8;                          \
                fbh[_t] = *(const f16x8*)&Bs[buf][0][_off];                    \
                fbl[_t] = *(const f16x8*)&Bs[buf][1][_off];                    \
            }                                                                  \
            __builtin_amdgcn_s_setprio(1);                                     \
            _Pragma("unroll")                                                  \
            for (int _mt = 0; _mt < 2; ++_mt)                                  \
                _Pragma("unroll")                                              \
                for (int _t = 0; _t < 4; ++_t) {                               \
                    acc[_mt][_t] = __builtin_amdgcn_mfma_f32_16x16x32_f16(     \
                        ah[_mt][(kh) * 4 + _k4], fbh[_t], acc[_mt][_t], 0, 0, 0); \
                    acc[_mt][_t] = __builtin_amdgcn_mfma_f32_16x16x32_f16(     \
                        al[_mt][(kh) * 4 + _k4], fbh[_t], acc[_mt][_t], 0, 0, 0); \
                    acc[_mt][_t] = __builtin_amdgcn_mfma_f32_16x16x32_f16(     \
                        ah[_mt][(kh) * 4 + _k4], fbl[_t], acc[_mt][_t], 0, 0, 0); \
                }                                                              \
            __builtin_amdgcn_s_setprio(0);                                     \
        }                                                                      \
    } while (0)

__global__ __launch_bounds__(512, 2) void vq_main(
        const float* __restrict__ z,
        const _Float16* __restrict__ ch, const _Float16* __restrict__ cl,
        const float* __restrict__ csq, const float* __restrict__ cb,
        float* __restrict__ zq, float* __restrict__ io) {
    // [buf][hi/lo][half = 4 chunks x 4096 f16]  -> 128 KB, 1 block/CU
    __shared__ _Float16 Bs[2][2][16384];

    const int tid  = threadIdx.x;
    const int w    = tid >> 6;                 // wave 0..7
    const int lane = tid & 63;
    const int quad = lane >> 4, lr = lane & 15;
    const int my   = w >> 1, nx = w & 1;       // 4 x 2 wave grid
    const int m0   = blockIdx.x * 128;

    // kick off DMA of half 0 into buf 0 before the A-load latency
    STAGE(0, 0);

    // ---- Phase 0: load my 2 m-tiles of z, split into hi/lo register frags ----
    // A-frag for (mt, kc8): A[m = my*32 + mt*16 + lr][k = kc8*32 + quad*8 + j]
    f16x8 ah[2][8], al[2][8];
    #pragma unroll
    for (int mt = 0; mt < 2; ++mt) {
        const float* zp = z + (size_t)(m0 + my * 32 + mt * 16 + lr) * NDIM
                        + quad * 8;
        #pragma unroll
        for (int c = 0; c < 8; ++c) {
            float4 a0 = *(const float4*)(zp + c * 32);
            float4 a1 = *(const float4*)(zp + c * 32 + 4);
            float v[8] = {a0.x, a0.y, a0.z, a0.w, a1.x, a1.y, a1.z, a1.w};
            #pragma unroll
            for (int e = 0; e < 8; ++e) {
                _Float16 h = (_Float16)v[e];
                ah[mt][c][e] = h;
                al[mt][c][e] = (_Float16)(v[e] - (float)h);
            }
        }
    }

    float bv[2][4];
    int   bi[2][4];
    #pragma unroll
    for (int mt = 0; mt < 2; ++mt)
        #pragma unroll
        for (int r = 0; r < 4; ++r) { bv[mt][r] = INFINITY; bi[mt][r] = 0x7fffffff; }

    f32x4 acc[2][4];
    #pragma unroll
    for (int mt = 0; mt < 2; ++mt)
        #pragma unroll
        for (int t = 0; t < 4; ++t) acc[mt][t] = (f32x4){0.f, 0.f, 0.f, 0.f};

    for (int strip = 0; strip < 8; ++strip) {
        // csq for my 4 column-tiles of this strip (L2-hot); these 4 loads are
        // absorbed by the vmcnt(12) margin below.
        float cs[4];
        #pragma unroll
        for (int t = 0; t < 4; ++t)
            cs[t] = csq[strip * 128 + (nx * 4 + t) * 16 + lr];

        // ---- phase kh=0: compute buf0 (half 2*strip), prefetch half 2*strip+1
        STAGE(2 * strip + 1, 1);
        // tail-in-flight: 8 stage calls + up to 4 csq loads -> 12 keeps the
        // prefetch airborne while guaranteeing half 2*strip has landed.
        asm volatile("s_waitcnt vmcnt(12)" ::: "memory");
        __builtin_amdgcn_s_barrier();
        __builtin_amdgcn_sched_barrier(0);
        COMPUTE(0, 0);
        __builtin_amdgcn_sched_barrier(0);
        __builtin_amdgcn_s_barrier();          // buf0 free for next stage

        // ---- phase kh=1: compute buf1 (half 2*strip+1), prefetch next half
        if (strip < 7) {
            STAGE(2 * strip + 2, 0);
            asm volatile("s_waitcnt vmcnt(8)" ::: "memory");
        } else {
            asm volatile("s_waitcnt vmcnt(0)" ::: "memory");
        }
        __builtin_amdgcn_s_barrier();
        __builtin_amdgcn_sched_barrier(0);
        COMPUTE(1, 1);
        __builtin_amdgcn_sched_barrier(0);
        __builtin_amdgcn_s_barrier();          // buf1 free for next stage

        // ---- fold this strip into the running per-lane argmin (regs only) ----
        #pragma unroll
        for (int mt = 0; mt < 2; ++mt)
            #pragma unroll
            for (int r = 0; r < 4; ++r)
                #pragma unroll
                for (int t = 0; t < 4; ++t) {
                    float v = cs[t] - 2.0f * acc[mt][t][r];
                    int   n = strip * 128 + (nx * 4 + t) * 16 + lr;
                    if (v < bv[mt][r] || (v == bv[mt][r] && n < bi[mt][r])) {
                        bv[mt][r] = v; bi[mt][r] = n;
                    }
                }
        #pragma unroll
        for (int mt = 0; mt < 2; ++mt)
            #pragma unroll
            for (int t = 0; t < 4; ++t) acc[mt][t] = (f32x4){0.f, 0.f, 0.f, 0.f};
    }

    // ---- butterfly over the 16 lanes sharing each row ----
    #pragma unroll
    for (int msk = 1; msk < 16; msk <<= 1)
        #pragma unroll
        for (int mt = 0; mt < 2; ++mt)
            #pragma unroll
            for (int r = 0; r < 4; ++r) {
                float ov = __shfl_xor(bv[mt][r], msk, 64);
                int   oi = __shfl_xor(bi[mt][r], msk, 64);
                if (ov < bv[mt][r] || (ov == bv[mt][r] && oi < bi[mt][r])) {
                    bv[mt][r] = ov; bi[mt][r] = oi;
                }
            }

    __syncthreads();                         // full drain; reuse LDS as scratch
    float* sval  = (float*)&Bs[0][0][0];     // [128][2]
    int*   sidx  = (int*)(sval + 256);       // [128][2]
    int*   bestS = (int*)(sval + 512);       // [128]

    if (lr == 0) {
        #pragma unroll
        for (int mt = 0; mt < 2; ++mt)
            #pragma unroll
            for (int r = 0; r < 4; ++r) {
                int row = my * 32 + mt * 16 + quad * 4 + r;   // 0..127
                sval[row * 2 + nx] = bv[mt][r];
                sidx[row * 2 + nx] = bi[mt][r];
            }
    }
    __syncthreads();

    if (tid < 128) {
        float v0 = sval[tid * 2], v1 = sval[tid * 2 + 1];
        int   i0 = sidx[tid * 2], i1 = sidx[tid * 2 + 1];
        bool take1 = (v1 < v0) || (v1 == v0 && i1 < i0);
        int best = take1 ? i1 : i0;
        bestS[tid] = best;
        io[m0 + tid] = (float)best;
    }
    __syncthreads();

    // ---- gather z_q: 128 rows x 1 KB from cb (L2-hot), coalesced float4 ----
    const int tr = tid >> 4, tc = tid & 15;
    #pragma unroll
    for (int p = 0; p < 4; ++p) {
        int row = p * 32 + tr;
        const float* src = cb + (size_t)bestS[row] * NDIM;
        float*       dst = zq + (size_t)(m0 + row) * NDIM;
        #pragma unroll
        for (int q = 0; q < 4; ++q) {
            int col = q * 64 + tc * 4;
            *(float4*)&dst[col] = *(const float4*)&src[col];
        }
    }
}

// ---------------------------------------------------------------------------
extern "C" void kernel_launch(void* const* d_in, const int* in_sizes, int n_in,
                              void* d_out, int out_size, void* d_ws, size_t ws_size,
                              hipStream_t stream) {
    const float* z  = (const float*)d_in[0];
    const float* cb = (const float*)d_in[1];

    float* zq = (float*)d_out;                        // 32768*256 floats
    float* io = (float*)d_out + (size_t)NTOK * NDIM;  // 32768 floats (indices)

    _Float16* ch  = (_Float16*)d_ws;                  // 0.5 MB
    _Float16* cl  = ch + (size_t)NCODE * NDIM;        // 0.5 MB
    float*    csq = (float*)(cl + (size_t)NCODE * NDIM);  // 4 KB

    prep_cb<<<NCODE * 32 / 256, 256, 0, stream>>>(cb, ch, cl, csq);

    vq_main<<<NTOK / 128, 512, 0, stream>>>(z, ch, cl, csq, cb, zq, io);
}

// Round 2
// 138.325 us; speedup vs baseline: 1.0961x; 1.0961x over previous
//
#include <hip/hip_runtime.h>
#include <math.h>

// Problem constants (B=8, T=4096, D=256, K=1024)
#define NTOK   32768
#define NDIM   256
#define NCODE  1024
#define CHUNK  4096           // f16 per (strip,kc8) chunk: 128 codes x 32 dims = 8 KB

typedef _Float16 f16x8 __attribute__((ext_vector_type(8)));
typedef float    f32x4 __attribute__((ext_vector_type(4)));

// async global->LDS DMA, 16 B per lane; LDS dst is wave-uniform base + lane*16
__device__ __forceinline__ void gld_lds16(const void* g, void* l) {
    __builtin_amdgcn_global_load_lds(
        (const __attribute__((address_space(1))) void*)g,
        (__attribute__((address_space(3))) void*)l, 16, 0, 0);
}

// ---------------------------------------------------------------------------
// Prep: split codebook (fp32) into f16 hi/lo planes, blocked k-major layout.
// Within-chunk layout (bank-conflict-free for main kernel's ds_read_b128,
// verified round 1: conflicts 4.2M -> 2K):
//   chunk = (strip = row/128, kc8 = dim/32); within chunk:
//   off_f16 = (r>>4)*512 + (g&3)*128 + (r&15)*8     (r = row%128, g&3 = k-quad)
// A wave's b128 read of one 16-row tile is a sequential 1 KB region.
// Plus exact fp32 row norms. ~1 MB total.
// ---------------------------------------------------------------------------
__global__ __launch_bounds__(256) void prep_cb(
        const float* __restrict__ cb,
        _Float16* __restrict__ ch, _Float16* __restrict__ cl,
        float* __restrict__ csq) {
    const int L   = blockIdx.x * 256 + threadIdx.x;   // 0..32767
    const int row = L >> 5;                           // code 0..1023
    const int g   = L & 31;                           // 8-elem group in 256 dims

    const float* src = cb + (size_t)row * NDIM + g * 8;
    float4 a0 = *(const float4*)src;
    float4 a1 = *(const float4*)(src + 4);
    float v[8] = {a0.x, a0.y, a0.z, a0.w, a1.x, a1.y, a1.z, a1.w};
    f16x8 hi, lo;
    float s = 0.f;
    #pragma unroll
    for (int e = 0; e < 8; ++e) {
        _Float16 h = (_Float16)v[e];
        hi[e] = h;
        lo[e] = (_Float16)(v[e] - (float)h);
        s += v[e] * v[e];
    }
    const int r = row & 127;
    const size_t dst = (size_t)((row >> 7) * 8 + (g >> 2)) * CHUNK
                     + (r >> 4) * 512 + (g & 3) * 128 + (r & 15) * 8;
    *(f16x8*)&ch[dst] = hi;
    *(f16x8*)&cl[dst] = lo;
    #pragma unroll
    for (int off = 16; off > 0; off >>= 1) s += __shfl_down(s, off, 32);
    if ((threadIdx.x & 31) == 0) csq[row] = s;
}

// ---------------------------------------------------------------------------
// Main: A-stationary fused VQ. 64 tokens/block, 256 threads = 4 waves in a
// 2x2 (my,nx) grid; 64 KB LDS -> 2 blocks/CU (cross-block overlap at
// barriers). Wave (my,nx): token rows [my*32,+32) register-resident for full
// K=256; code-column half nx of every strip.
// K-loop granularity: QUARTER = 2 chunks (2 kc8) = 16 KB hi + 16 KB lo.
// Double-buffered (2 x 32 KB) with counted-vmcnt prefetch: stage quarter Q+1
// while computing Q; vmcnt never drains to 0 mid-loop. No sched_barrier
// fences (round-1 lesson: order-pinning defeats the scheduler).
// 3-pass f16 MFMA (ah.bh + al.bh + ah.bl); per-lane running argmin per strip.
// Layouts (verified): A/B frag [row=lane&15][k=(lane>>4)*8+j]; D col=lane&15,
// row=(lane>>4)*4+reg.
// ---------------------------------------------------------------------------

// Stage quarter Q (global chunks 2Q, 2Q+1) into buffer `buf`.
// Per wave: 4 KB hi + 4 KB lo = 8 gld_lds16 of 1 KB each (vmcnt +8).
#define STAGE(Q, buf)                                                          \
    do {                                                                       \
        const size_t _sb = (size_t)(Q) * 8192 + w * 2048 + lane * 8;           \
        const int    _lb = w * 2048;                                           \
        _Pragma("unroll")                                                      \
        for (int _i = 0; _i < 4; ++_i) {                                       \
            gld_lds16(ch + _sb + _i * 512, &Bs[buf][0][_lb + _i * 512]);       \
            gld_lds16(cl + _sb + _i * 512, &Bs[buf][1][_lb + _i * 512]);       \
        }                                                                      \
    } while (0)

// Compute quarter q (kc8 = 2q, 2q+1 within the strip) from buffer `buf`.
#define COMPUTE(q, buf)                                                        \
    do {                                                                       \
        _Pragma("unroll")                                                      \
        for (int _kc = 0; _kc < 2; ++_kc) {                                    \
            const int _kg = (q) * 2 + _kc;                                     \
            f16x8 fbh[4], fbl[4];                                              \
            _Pragma("unroll")                                                  \
            for (int _t = 0; _t < 4; ++_t) {                                   \
                const int _off = _kc * 4096 + (nx * 4 + _t) * 512              \
                               + quad * 128 + lr * 8;                          \
                fbh[_t] = *(const f16x8*)&Bs[buf][0][_off];                    \
                fbl[_t] = *(const f16x8*)&Bs[buf][1][_off];                    \
            }                                                                  \
            __builtin_amdgcn_s_setprio(1);                                     \
            _Pragma("unroll")                                                  \
            for (int _mt = 0; _mt < 2; ++_mt)                                  \
                _Pragma("unroll")                                              \
                for (int _t = 0; _t < 4; ++_t) {                               \
                    acc[_mt][_t] = __builtin_amdgcn_mfma_f32_16x16x32_f16(     \
                        ah[_mt][_kg], fbh[_t], acc[_mt][_t], 0, 0, 0);         \
                    acc[_mt][_t] = __builtin_amdgcn_mfma_f32_16x16x32_f16(     \
                        al[_mt][_kg], fbh[_t], acc[_mt][_t], 0, 0, 0);         \
                    acc[_mt][_t] = __builtin_amdgcn_mfma_f32_16x16x32_f16(     \
                        ah[_mt][_kg], fbl[_t], acc[_mt][_t], 0, 0, 0);         \
                }                                                              \
            __builtin_amdgcn_s_setprio(0);                                     \
        }                                                                      \
    } while (0)

__global__ __launch_bounds__(256, 2) void vq_main(
        const float* __restrict__ z,
        const _Float16* __restrict__ ch, const _Float16* __restrict__ cl,
        const float* __restrict__ csq, const float* __restrict__ cb,
        float* __restrict__ zq, float* __restrict__ io) {
    // [buf][hi/lo][quarter = 2 chunks x 4096 f16] -> 64 KB, 2 blocks/CU
    __shared__ _Float16 Bs[2][2][8192];

    const int tid  = threadIdx.x;
    const int w    = tid >> 6;                 // wave 0..3
    const int lane = tid & 63;
    const int quad = lane >> 4, lr = lane & 15;
    const int my   = w >> 1, nx = w & 1;       // 2 x 2 wave grid
    const int m0   = blockIdx.x * 64;

    // kick off DMA of quarter 0 into buf 0 ahead of the A-load latency
    STAGE(0, 0);

    // ---- Phase 0: load my 2 m-tiles of z, split into hi/lo register frags ----
    // A-frag for (mt, kc8): A[m = my*32 + mt*16 + lr][k = kc8*32 + quad*8 + j]
    f16x8 ah[2][8], al[2][8];
    #pragma unroll
    for (int mt = 0; mt < 2; ++mt) {
        const float* zp = z + (size_t)(m0 + my * 32 + mt * 16 + lr) * NDIM
                        + quad * 8;
        #pragma unroll
        for (int c = 0; c < 8; ++c) {
            float4 a0 = *(const float4*)(zp + c * 32);
            float4 a1 = *(const float4*)(zp + c * 32 + 4);
            float v[8] = {a0.x, a0.y, a0.z, a0.w, a1.x, a1.y, a1.z, a1.w};
            #pragma unroll
            for (int e = 0; e < 8; ++e) {
                _Float16 h = (_Float16)v[e];
                ah[mt][c][e] = h;
                al[mt][c][e] = (_Float16)(v[e] - (float)h);
            }
        }
    }

    float bv[2][4];
    int   bi[2][4];
    #pragma unroll
    for (int mt = 0; mt < 2; ++mt)
        #pragma unroll
        for (int r = 0; r < 4; ++r) { bv[mt][r] = INFINITY; bi[mt][r] = 0x7fffffff; }

    f32x4 acc[2][4];
    #pragma unroll
    for (int mt = 0; mt < 2; ++mt)
        #pragma unroll
        for (int t = 0; t < 4; ++t) acc[mt][t] = (f32x4){0.f, 0.f, 0.f, 0.f};

    for (int strip = 0; strip < 8; ++strip) {
        const int Q0 = strip * 4;

        // csq for my 4 column-tiles of this strip (L2-hot). Issued before the
        // q=0 prefetch; the vmcnt(12) margin below accounts for these 4 loads.
        float cs[4];
        #pragma unroll
        for (int t = 0; t < 4; ++t)
            cs[t] = csq[strip * 128 + (nx * 4 + t) * 16 + lr];

        // q=0: queue [STAGE(Q0) 8 | csq 4 | STAGE(Q0+1) 8] -> vmcnt(12)
        //      drains exactly STAGE(Q0); prefetch + csq stay airborne.
        STAGE(Q0 + 1, 1);
        asm volatile("s_waitcnt vmcnt(12)" ::: "memory");
        __builtin_amdgcn_s_barrier();
        COMPUTE(0, 0);
        __builtin_amdgcn_s_barrier();          // buf0 free for overwrite

        // q=1: queue [csq 4 | STAGE(Q0+1) 8 | STAGE(Q0+2) 8] -> vmcnt(8)
        STAGE(Q0 + 2, 0);
        asm volatile("s_waitcnt vmcnt(8)" ::: "memory");
        __builtin_amdgcn_s_barrier();
        COMPUTE(1, 1);
        __builtin_amdgcn_s_barrier();

        // q=2: queue [STAGE(Q0+2) 8 | STAGE(Q0+3) 8] -> vmcnt(8)
        STAGE(Q0 + 3, 1);
        asm volatile("s_waitcnt vmcnt(8)" ::: "memory");
        __builtin_amdgcn_s_barrier();
        COMPUTE(2, 0);
        __builtin_amdgcn_s_barrier();

        // q=3: prefetch next strip's first quarter (except final strip)
        if (strip < 7) {
            STAGE(Q0 + 4, 0);
            asm volatile("s_waitcnt vmcnt(8)" ::: "memory");
        } else {
            asm volatile("s_waitcnt vmcnt(0)" ::: "memory");
        }
        __builtin_amdgcn_s_barrier();
        COMPUTE(3, 1);
        __builtin_amdgcn_s_barrier();

        // ---- fold this strip into the running per-lane argmin (regs only) ----
        #pragma unroll
        for (int mt = 0; mt < 2; ++mt)
            #pragma unroll
            for (int r = 0; r < 4; ++r)
                #pragma unroll
                for (int t = 0; t < 4; ++t) {
                    float v = cs[t] - 2.0f * acc[mt][t][r];
                    int   n = strip * 128 + (nx * 4 + t) * 16 + lr;
                    if (v < bv[mt][r] || (v == bv[mt][r] && n < bi[mt][r])) {
                        bv[mt][r] = v; bi[mt][r] = n;
                    }
                }
        #pragma unroll
        for (int mt = 0; mt < 2; ++mt)
            #pragma unroll
            for (int t = 0; t < 4; ++t) acc[mt][t] = (f32x4){0.f, 0.f, 0.f, 0.f};
    }

    // ---- butterfly over the 16 lanes sharing each row ----
    #pragma unroll
    for (int msk = 1; msk < 16; msk <<= 1)
        #pragma unroll
        for (int mt = 0; mt < 2; ++mt)
            #pragma unroll
            for (int r = 0; r < 4; ++r) {
                float ov = __shfl_xor(bv[mt][r], msk, 64);
                int   oi = __shfl_xor(bi[mt][r], msk, 64);
                if (ov < bv[mt][r] || (ov == bv[mt][r] && oi < bi[mt][r])) {
                    bv[mt][r] = ov; bi[mt][r] = oi;
                }
            }

    __syncthreads();                         // done with Bs; reuse as scratch
    float* sval  = (float*)&Bs[0][0][0];     // [64][2]
    int*   sidx  = (int*)&Bs[0][0][512];     // [64][2]
    int*   bestS = (int*)&Bs[0][0][1024];    // [64]

    if (lr == 0) {
        #pragma unroll
        for (int mt = 0; mt < 2; ++mt)
            #pragma unroll
            for (int r = 0; r < 4; ++r) {
                int row = my * 32 + mt * 16 + quad * 4 + r;   // 0..63
                sval[row * 2 + nx] = bv[mt][r];
                sidx[row * 2 + nx] = bi[mt][r];
            }
    }
    __syncthreads();

    if (tid < 64) {
        float v0 = sval[tid * 2], v1 = sval[tid * 2 + 1];
        int   i0 = sidx[tid * 2], i1 = sidx[tid * 2 + 1];
        bool take1 = (v1 < v0) || (v1 == v0 && i1 < i0);
        int best = take1 ? i1 : i0;
        bestS[tid] = best;
        io[m0 + tid] = (float)best;
    }
    __syncthreads();

    // ---- gather z_q: 64 rows x 1 KB from cb (L2-hot), coalesced float4 ----
    const int tr = tid >> 4, tc = tid & 15;
    #pragma unroll
    for (int p = 0; p < 4; ++p) {
        int row = p * 16 + tr;
        const float* src = cb + (size_t)bestS[row] * NDIM;
        float*       dst = zq + (size_t)(m0 + row) * NDIM;
        #pragma unroll
        for (int q = 0; q < 4; ++q) {
            int col = q * 64 + tc * 4;
            *(float4*)&dst[col] = *(const float4*)&src[col];
        }
    }
}

// ---------------------------------------------------------------------------
extern "C" void kernel_launch(void* const* d_in, const int* in_sizes, int n_in,
                              void* d_out, int out_size, void* d_ws, size_t ws_size,
                              hipStream_t stream) {
    const float* z  = (const float*)d_in[0];
    const float* cb = (const float*)d_in[1];

    float* zq = (float*)d_out;                        // 32768*256 floats
    float* io = (float*)d_out + (size_t)NTOK * NDIM;  // 32768 floats (indices)

    _Float16* ch  = (_Float16*)d_ws;                  // 0.5 MB
    _Float16* cl  = ch + (size_t)NCODE * NDIM;        // 0.5 MB
    float*    csq = (float*)(cl + (size_t)NCODE * NDIM);  // 4 KB

    prep_cb<<<NCODE * 32 / 256, 256, 0, stream>>>(cb, ch, cl, csq);

    vq_main<<<NTOK / 64, 256, 0, stream>>>(z, ch, cl, csq, cb, zq, io);
}

// Round 3
// 133.865 us; speedup vs baseline: 1.1326x; 1.0333x over previous
//
#include <hip/hip_runtime.h>
#include <math.h>

// Problem constants (B=8, T=4096, D=256, K=1024)
#define NTOK   32768
#define NDIM   256
#define NCODE  1024
#define CHUNK  4096           // f16 per (strip,kc8) chunk: 128 codes x 32 dims = 8 KB

typedef _Float16 f16x8 __attribute__((ext_vector_type(8)));
typedef float    f32x4 __attribute__((ext_vector_type(4)));

// async global->LDS DMA, 16 B per lane; LDS dst is wave-uniform base + lane*16
__device__ __forceinline__ void gld_lds16(const void* g, void* l) {
    __builtin_amdgcn_global_load_lds(
        (const __attribute__((address_space(1))) void*)g,
        (__attribute__((address_space(3))) void*)l, 16, 0, 0);
}

// ---------------------------------------------------------------------------
// Prep: split codebook (fp32) into f16 hi/lo planes, blocked k-major layout.
// Within-chunk layout (bank-conflict-free for main kernel's ds_read_b128,
// verified round 1: conflicts 4.2M -> 2K):
//   chunk = (strip = row/128, kc8 = dim/32); within chunk:
//   off_f16 = (r>>4)*512 + (g&3)*128 + (r&15)*8     (r = row%128, g&3 = k-quad)
// A wave's b128 read of one 16-row tile is a sequential 1 KB region.
// Plus exact fp32 row norms. ~1 MB total.
// ---------------------------------------------------------------------------
__global__ __launch_bounds__(256) void prep_cb(
        const float* __restrict__ cb,
        _Float16* __restrict__ ch, _Float16* __restrict__ cl,
        float* __restrict__ csq) {
    const int L   = blockIdx.x * 256 + threadIdx.x;   // 0..32767
    const int row = L >> 5;                           // code 0..1023
    const int g   = L & 31;                           // 8-elem group in 256 dims

    const float* src = cb + (size_t)row * NDIM + g * 8;
    float4 a0 = *(const float4*)src;
    float4 a1 = *(const float4*)(src + 4);
    float v[8] = {a0.x, a0.y, a0.z, a0.w, a1.x, a1.y, a1.z, a1.w};
    f16x8 hi, lo;
    float s = 0.f;
    #pragma unroll
    for (int e = 0; e < 8; ++e) {
        _Float16 h = (_Float16)v[e];
        hi[e] = h;
        lo[e] = (_Float16)(v[e] - (float)h);
        s += v[e] * v[e];
    }
    const int r = row & 127;
    const size_t dst = (size_t)((row >> 7) * 8 + (g >> 2)) * CHUNK
                     + (r >> 4) * 512 + (g & 3) * 128 + (r & 15) * 8;
    *(f16x8*)&ch[dst] = hi;
    *(f16x8*)&cl[dst] = lo;
    #pragma unroll
    for (int off = 16; off > 0; off >>= 1) s += __shfl_down(s, off, 32);
    if ((threadIdx.x & 31) == 0) csq[row] = s;
}

// ---------------------------------------------------------------------------
// Main: A-stationary fused VQ, 8-phase fine interleave (T3+T4 port).
// 64 tokens/block, 256 threads = 4 waves in a 2x2 (my,nx) grid; ring of 4
// chunk-slots (64 KB) + 4 KB csq table -> 68 KB LDS, 2 blocks/CU.
// Phase = 1 kc8 chunk: {8 ds_read_b128 | issue STAGE(g+3) | vmcnt(8) |
// s_barrier | lgkmcnt(0) | setprio(1) 24 MFMA setprio(0) | s_barrier}.
// vmcnt(8) keeps 2 chunk-stages airborne across barriers (never 0 mid-loop);
// prefetch distance 3 phases. csq lives in LDS (prologue DMA) so the VMEM
// queue contains ONLY staging ops and the counted waits are exact.
// Per-strip acc re-zero eliminated via zero-C on the strip's first MFMA pass.
// 3-pass f16 MFMA (ah.bh + al.bh + ah.bl); per-lane running argmin per strip.
// Layouts (verified): A/B frag [row=lane&15][k=(lane>>4)*8+j]; D col=lane&15,
// row=(lane>>4)*4+reg.
// ---------------------------------------------------------------------------

// One phase. p = static phase index 0..7 (slot = p&3; A-frag kc8 = p since
// every strip spans the same 256 dims). GB = strip*8 (runtime OK: only used
// in the DMA source address). DOSTAGE/WK/FIRSTZ are compile-time.
#define PHASE(p, GB, DOSTAGE, WK, FIRSTZ) do {                               \
    const int _sl = (p) & 3;                                                 \
    f16x8 fbh[4], fbl[4];                                                    \
    _Pragma("unroll")                                                        \
    for (int _t = 0; _t < 4; ++_t) {                                         \
        fbh[_t] = *(const f16x8*)&Bs[_sl][0][boff[_t]];                      \
        fbl[_t] = *(const f16x8*)&Bs[_sl][1][boff[_t]];                      \
    }                                                                        \
    if (DOSTAGE) {                                                           \
        const size_t _s  = (size_t)((GB) + (p) + 3) * CHUNK + tid * 8;       \
        const int    _dsl = ((p) + 3) & 3;                                   \
        const int    _d   = tid * 8;                                         \
        gld_lds16(ch + _s,        &Bs[_dsl][0][_d]);                         \
        gld_lds16(ch + _s + 2048, &Bs[_dsl][0][_d + 2048]);                  \
        gld_lds16(cl + _s,        &Bs[_dsl][1][_d]);                         \
        gld_lds16(cl + _s + 2048, &Bs[_dsl][1][_d + 2048]);                  \
    }                                                                        \
    asm volatile("s_waitcnt vmcnt(" #WK ")" ::: "memory");                   \
    __builtin_amdgcn_s_barrier();                                            \
    asm volatile("s_waitcnt lgkmcnt(0)" ::: "memory");                       \
    __builtin_amdgcn_s_setprio(1);                                           \
    _Pragma("unroll")                                                        \
    for (int _mt = 0; _mt < 2; ++_mt)                                        \
        _Pragma("unroll")                                                    \
        for (int _t = 0; _t < 4; ++_t) {                                     \
            acc[_mt][_t] = __builtin_amdgcn_mfma_f32_16x16x32_f16(           \
                ah[_mt][(p)], fbh[_t],                                       \
                (FIRSTZ) ? zz : acc[_mt][_t], 0, 0, 0);                      \
            acc[_mt][_t] = __builtin_amdgcn_mfma_f32_16x16x32_f16(           \
                al[_mt][(p)], fbh[_t], acc[_mt][_t], 0, 0, 0);               \
            acc[_mt][_t] = __builtin_amdgcn_mfma_f32_16x16x32_f16(           \
                ah[_mt][(p)], fbl[_t], acc[_mt][_t], 0, 0, 0);               \
        }                                                                    \
    __builtin_amdgcn_s_setprio(0);                                           \
    __builtin_amdgcn_s_barrier();                                            \
} while (0)

// Fold strip S's dot products into the running per-lane argmin (regs + LDS
// csq reads only -- no VMEM, so the vmcnt ledger is untouched).
#define FOLD(S) do {                                                         \
    float cs[4];                                                             \
    _Pragma("unroll")                                                        \
    for (int _t = 0; _t < 4; ++_t)                                           \
        cs[_t] = csq_lds[(S) * 128 + (nx * 4 + _t) * 16 + lr];               \
    _Pragma("unroll")                                                        \
    for (int _mt = 0; _mt < 2; ++_mt)                                        \
        _Pragma("unroll")                                                    \
        for (int _r = 0; _r < 4; ++_r)                                       \
            _Pragma("unroll")                                                \
            for (int _t = 0; _t < 4; ++_t) {                                 \
                float _v = cs[_t] - 2.0f * acc[_mt][_t][_r];                 \
                int   _n = (S) * 128 + (nx * 4 + _t) * 16 + lr;              \
                if (_v < bv[_mt][_r] ||                                      \
                    (_v == bv[_mt][_r] && _n < bi[_mt][_r])) {               \
                    bv[_mt][_r] = _v; bi[_mt][_r] = _n;                      \
                }                                                            \
            }                                                                \
} while (0)

__global__ __launch_bounds__(256, 2) void vq_main(
        const float* __restrict__ z,
        const _Float16* __restrict__ ch, const _Float16* __restrict__ cl,
        const float* __restrict__ csq, const float* __restrict__ cb,
        float* __restrict__ zq, float* __restrict__ io) {
    // ring of 4 chunk-slots x {hi,lo} x 8 KB = 64 KB, + 4 KB csq -> 68 KB
    __shared__ _Float16 Bs[4][2][4096];
    __shared__ float    csq_lds[1024];

    const int tid  = threadIdx.x;
    const int w    = tid >> 6;
    const int lane = tid & 63;
    const int quad = lane >> 4, lr = lane & 15;
    const int my   = w >> 1, nx = w & 1;       // 2 x 2 wave grid
    const int m0   = blockIdx.x * 64;

    // ---- prologue DMA: csq table + chunk slots 0..2 (13 vmem ops) ----
    gld_lds16(csq + tid * 4, &csq_lds[tid * 4]);
    #pragma unroll
    for (int c = 0; c < 3; ++c) {
        const size_t sb = (size_t)c * CHUNK + tid * 8;
        gld_lds16(ch + sb,        &Bs[c][0][tid * 8]);
        gld_lds16(ch + sb + 2048, &Bs[c][0][tid * 8 + 2048]);
        gld_lds16(cl + sb,        &Bs[c][1][tid * 8]);
        gld_lds16(cl + sb + 2048, &Bs[c][1][tid * 8 + 2048]);
    }

    // ---- load my 2 m-tiles of z, split into hi/lo register frags ----
    // A-frag for (mt, kc8): A[m = my*32 + mt*16 + lr][k = kc8*32 + quad*8 + j]
    f16x8 ah[2][8], al[2][8];
    #pragma unroll
    for (int mt = 0; mt < 2; ++mt) {
        const float* zp = z + (size_t)(m0 + my * 32 + mt * 16 + lr) * NDIM
                        + quad * 8;
        #pragma unroll
        for (int c = 0; c < 8; ++c) {
            float4 a0 = *(const float4*)(zp + c * 32);
            float4 a1 = *(const float4*)(zp + c * 32 + 4);
            float v[8] = {a0.x, a0.y, a0.z, a0.w, a1.x, a1.y, a1.z, a1.w};
            #pragma unroll
            for (int e = 0; e < 8; ++e) {
                _Float16 h = (_Float16)v[e];
                ah[mt][c][e] = h;
                al[mt][c][e] = (_Float16)(v[e] - (float)h);
            }
        }
    }

    int boff[4];
    #pragma unroll
    for (int t = 0; t < 4; ++t)
        boff[t] = (nx * 4 + t) * 512 + quad * 128 + lr * 8;

    float bv[2][4];
    int   bi[2][4];
    #pragma unroll
    for (int mt = 0; mt < 2; ++mt)
        #pragma unroll
        for (int r = 0; r < 4; ++r) { bv[mt][r] = INFINITY; bi[mt][r] = 0x7fffffff; }

    const f32x4 zz = (f32x4){0.f, 0.f, 0.f, 0.f};
    f32x4 acc[2][4];
    #pragma unroll
    for (int mt = 0; mt < 2; ++mt)
        #pragma unroll
        for (int t = 0; t < 4; ++t) acc[mt][t] = zz;

    // one-time full drain (prologue only) + sync; steady-state in-flight
    // rebuilds over phases 0-2 (phase-0/1 vmcnt(8) are no-ops, by design).
    asm volatile("s_waitcnt vmcnt(0)" ::: "memory");
    __syncthreads();

    // ---- main loop: strips 0..6 uniform, strip 7 peeled for drain tail ----
    for (int s = 0; s < 7; ++s) {
        const int gb = s * 8;
        PHASE(0, gb, 1, 8, 1);
        PHASE(1, gb, 1, 8, 0);
        PHASE(2, gb, 1, 8, 0);
        PHASE(3, gb, 1, 8, 0);
        PHASE(4, gb, 1, 8, 0);
        PHASE(5, gb, 1, 8, 0);
        PHASE(6, gb, 1, 8, 0);
        PHASE(7, gb, 1, 8, 0);
        FOLD(s);
    }
    {
        const int gb = 56;
        PHASE(0, gb, 1, 8, 1);
        PHASE(1, gb, 1, 8, 0);
        PHASE(2, gb, 1, 8, 0);
        PHASE(3, gb, 1, 8, 0);
        PHASE(4, gb, 1, 8, 0);   // stages chunk 63 (the last)
        PHASE(5, gb, 0, 4, 0);   // drain chunk 62
        PHASE(6, gb, 0, 0, 0);   // drain chunk 63
        PHASE(7, gb, 0, 0, 0);
        FOLD(7);
    }

    // ---- butterfly over the 16 lanes sharing each row ----
    #pragma unroll
    for (int msk = 1; msk < 16; msk <<= 1)
        #pragma unroll
        for (int mt = 0; mt < 2; ++mt)
            #pragma unroll
            for (int r = 0; r < 4; ++r) {
                float ov = __shfl_xor(bv[mt][r], msk, 64);
                int   oi = __shfl_xor(bi[mt][r], msk, 64);
                if (ov < bv[mt][r] || (ov == bv[mt][r] && oi < bi[mt][r])) {
                    bv[mt][r] = ov; bi[mt][r] = oi;
                }
            }

    __syncthreads();                         // done with Bs; reuse as scratch
    float* sval  = (float*)&Bs[0][0][0];     // [64][2]
    int*   sidx  = (int*)&Bs[0][0][512];     // [64][2]
    int*   bestS = (int*)&Bs[0][0][1024];    // [64]

    if (lr == 0) {
        #pragma unroll
        for (int mt = 0; mt < 2; ++mt)
            #pragma unroll
            for (int r = 0; r < 4; ++r) {
                int row = my * 32 + mt * 16 + quad * 4 + r;   // 0..63
                sval[row * 2 + nx] = bv[mt][r];
                sidx[row * 2 + nx] = bi[mt][r];
            }
    }
    __syncthreads();

    if (tid < 64) {
        float v0 = sval[tid * 2], v1 = sval[tid * 2 + 1];
        int   i0 = sidx[tid * 2], i1 = sidx[tid * 2 + 1];
        bool take1 = (v1 < v0) || (v1 == v0 && i1 < i0);
        int best = take1 ? i1 : i0;
        bestS[tid] = best;
        io[m0 + tid] = (float)best;
    }
    __syncthreads();

    // ---- gather z_q: 64 rows x 1 KB from cb (L2-hot), coalesced float4 ----
    const int tr = tid >> 4, tc = tid & 15;
    #pragma unroll
    for (int p = 0; p < 4; ++p) {
        int row = p * 16 + tr;
        const float* src = cb + (size_t)bestS[row] * NDIM;
        float*       dst = zq + (size_t)(m0 + row) * NDIM;
        #pragma unroll
        for (int q = 0; q < 4; ++q) {
            int col = q * 64 + tc * 4;
            *(float4*)&dst[col] = *(const float4*)&src[col];
        }
    }
}

// ---------------------------------------------------------------------------
extern "C" void kernel_launch(void* const* d_in, const int* in_sizes, int n_in,
                              void* d_out, int out_size, void* d_ws, size_t ws_size,
                              hipStream_t stream) {
    const float* z  = (const float*)d_in[0];
    const float* cb = (const float*)d_in[1];

    float* zq = (float*)d_out;                        // 32768*256 floats
    float* io = (float*)d_out + (size_t)NTOK * NDIM;  // 32768 floats (indices)

    _Float16* ch  = (_Float16*)d_ws;                  // 0.5 MB
    _Float16* cl  = ch + (size_t)NCODE * NDIM;        // 0.5 MB
    float*    csq = (float*)(cl + (size_t)NCODE * NDIM);  // 4 KB

    prep_cb<<<NCODE * 32 / 256, 256, 0, stream>>>(cb, ch, cl, csq);

    vq_main<<<NTOK / 64, 256, 0, stream>>>(z, ch, cl, csq, cb, zq, io);
}